// Round 1
// baseline (1341.868 us; speedup 1.0000x reference)
//
#include <hip/hip_runtime.h>
#include <cmath>

// ---------------------------------------------------------------------------
// MWT (multiwavelet transform) for B=32, N=8192, c=16, k=4, modes=64.
// Structure:
//   13 decomposition levels: decompose -> fwd DFT GEMM -> spectral mix -> inv DFT GEMM
//   t0 linear map at coarsest level
//   13 reconstruction levels
// DFT is done as dense truncated-DFT GEMMs (l<=64 modes), not FFT.
// ---------------------------------------------------------------------------

struct Mat84 { float v[8][4]; };
struct Ptrs6 { const float* src[6]; float* dst[6]; };

// ---------------- host: Alpert/Legendre filter construction (k=4) ----------
static double proj_half_h(const double* a, const double* b, bool upper) {
  double prod[7] = {0, 0, 0, 0, 0, 0, 0};
  for (int i = 0; i < 4; i++)
    for (int j = 0; j < 4; j++)
      prod[i + j] += a[i] * b[j];
  for (int n = 0; n < 7; n++)
    if (fabs(prod[n]) < 1e-8) prod[n] = 0.0;
  double s = 0.0;
  for (int n = 0; n < 7; n++) {
    double w = upper ? (1.0 - pow(0.5, n + 1)) / (n + 1) : pow(0.5, n + 1) / (n + 1);
    s += prod[n] * w;
  }
  return s;
}
static double polyval4(const double* c, double x) {
  return c[0] + x * (c[1] + x * (c[2] + x * c[3]));
}

static void compute_filters(Mat84& ecs, Mat84& ecd, Mat84& rce, Mat84& rco) {
  const double leg[4][4] = {{1, 0, 0, 0}, {0, 1, 0, 0}, {-0.5, 0, 1.5, 0}, {0, -1.5, 0, 2.5}};
  double phi_c[4][4] = {}, phi2x_c[4][4] = {};
  const double s2 = sqrt(2.0);
  for (int ki = 0; ki < 4; ki++) {
    double a[4] = {0, 0, 0, 0};
    for (int j = 3; j >= 0; j--) {           // compose with (2x-1), Horner
      double na[4];
      for (int t = 0; t < 4; t++) { double v = -a[t]; if (t > 0) v += 2.0 * a[t - 1]; na[t] = v; }
      na[0] += leg[ki][j];
      for (int t = 0; t < 4; t++) a[t] = na[t];
    }
    for (int t = 0; t < 4; t++) phi_c[ki][t] = sqrt(2.0 * ki + 1.0) * a[t];
    double bb[4] = {0, 0, 0, 0};
    for (int j = 3; j >= 0; j--) {           // compose with (4x-1)
      double nb[4];
      for (int t = 0; t < 4; t++) { double v = -bb[t]; if (t > 0) v += 4.0 * bb[t - 1]; nb[t] = v; }
      nb[0] += leg[ki][j];
      for (int t = 0; t < 4; t++) bb[t] = nb[t];
    }
    for (int t = 0; t < 4; t++) phi2x_c[ki][t] = s2 * sqrt(2.0 * ki + 1.0) * bb[t];
  }
  double psi1[4][4] = {}, psi2[4][4] = {};
  for (int ki = 0; ki < 4; ki++) {
    for (int t = 0; t < 4; t++) { psi1[ki][t] = phi2x_c[ki][t]; psi2[ki][t] = 0.0; }
    for (int i = 0; i < 4; i++) {
      double p = proj_half_h(phi2x_c[ki], phi_c[i], false);
      for (int t = 0; t < 4; t++) { psi1[ki][t] -= p * phi_c[i][t]; psi2[ki][t] -= p * phi_c[i][t]; }
    }
    for (int j = 0; j < ki; j++) {
      double p = proj_half_h(phi2x_c[ki], psi1[j], false);
      for (int t = 0; t < 4; t++) { psi1[ki][t] -= p * psi1[j][t]; psi2[ki][t] -= p * psi2[j][t]; }
    }
    double n1 = proj_half_h(psi1[ki], psi1[ki], false);
    double n2 = proj_half_h(psi2[ki], psi2[ki], true);
    double nr = sqrt(n1 + n2);
    for (int t = 0; t < 4; t++) { psi1[ki][t] /= nr; psi2[ki][t] /= nr; }
    for (int t = 0; t < 4; t++) {
      if (fabs(psi1[ki][t]) < 1e-8) psi1[ki][t] = 0.0;
      if (fabs(psi2[ki][t]) < 1e-8) psi2[ki][t] = 0.0;
    }
  }
  const double tq[4] = {-0.8611363115940526, -0.3399810435848563,
                        0.3399810435848563, 0.8611363115940526};
  const double wq[4] = {0.34785484513745385, 0.6521451548625461,
                        0.6521451548625461, 0.34785484513745385};
  double H0[4][4], H1[4][4], G0[4][4], G1[4][4];
  for (int ki = 0; ki < 4; ki++)
    for (int kp = 0; kp < 4; kp++) {
      double h0 = 0, h1 = 0, g0 = 0, g1 = 0;
      for (int m = 0; m < 4; m++) {
        double xm = (tq[m] + 1.0) * 0.5, wm = wq[m] * 0.5;
        double pk = polyval4(phi_c[kp], xm);
        h0 += wm * polyval4(phi_c[ki], xm * 0.5) * pk;
        h1 += wm * polyval4(phi_c[ki], (xm + 1.0) * 0.5) * pk;
        g0 += wm * polyval4(psi1[ki], xm * 0.5) * pk;        // x<=0.5 branch
        g1 += wm * polyval4(psi2[ki], (xm + 1.0) * 0.5) * pk; // x>0.5 branch
      }
      H0[ki][kp] = h0 / s2; H1[ki][kp] = h1 / s2; G0[ki][kp] = g0 / s2; G1[ki][kp] = g1 / s2;
    }
  for (int i = 0; i < 4; i++)
    for (int j = 0; j < 4; j++) {
      if (fabs(H0[i][j]) < 1e-8) H0[i][j] = 0.0;
      if (fabs(H1[i][j]) < 1e-8) H1[i][j] = 0.0;
      if (fabs(G0[i][j]) < 1e-8) G0[i][j] = 0.0;
      if (fabs(G1[i][j]) < 1e-8) G1[i][j] = 0.0;
    }
  for (int j = 0; j < 4; j++)
    for (int kk = 0; kk < 4; kk++) {
      ecs.v[j][kk]     = (float)H0[kk][j];   // EC_S = [H0^T ; H1^T]
      ecs.v[j + 4][kk] = (float)H1[kk][j];
      ecd.v[j][kk]     = (float)G0[kk][j];   // EC_D = [G0^T ; G1^T]
      ecd.v[j + 4][kk] = (float)G1[kk][j];
      rce.v[j][kk]     = (float)H0[j][kk];   // RC_E = [H0 ; G0]
      rce.v[j + 4][kk] = (float)G0[j][kk];
      rco.v[j][kk]     = (float)H1[j][kk];   // RC_O = [H1 ; G1]
      rco.v[j + 4][kk] = (float)G1[j][kk];
    }
}

// ---------------- device kernels -------------------------------------------

// Transpose weights (i,o,m) -> (m,i,o) for coalesced reads in spectral mix.
__global__ void transpose_w(Ptrs6 p) {
  __shared__ float tile[64][65];
  int i = blockIdx.x, a = blockIdx.y;
  const float* w = p.src[a];
  float* wt = p.dst[a];
  int m = threadIdx.x & 63, orow = threadIdx.x >> 6;
  for (int o = orow; o < 64; o += 4) tile[o][m] = w[((i * 64 + o) << 6) + m];
  __syncthreads();
  int o = threadIdx.x & 63, mrow = threadIdx.x >> 6;
  for (int mm = mrow; mm < 64; mm += 4) wt[((mm * 64 + i) << 6) + o] = tile[o][mm];
}

// Fill fwd (2l x Nl) and inv (Nl x 2l) truncated-DFT matrices for one level.
__global__ void twiddle_kernel(float* __restrict__ fwd, float* __restrict__ inv,
                               int Nl, int l) {
  int idx = blockIdx.x * 256 + threadIdx.x;
  if (idx >= l * Nl) return;
  int n = idx % Nl, m = idx / Nl;
  int t = (m * n) & (Nl - 1);
  float ang = 6.2831853071795864769f * ((float)t / (float)Nl);
  float s, c;
  sincosf(ang, &s, &c);
  fwd[(size_t)m * Nl + n] = c;           // Re row
  fwd[(size_t)(l + m) * Nl + n] = -s;    // Im row
  float cm = (m == 0 || 2 * m == Nl) ? 1.0f : 2.0f;
  float sc = cm / (float)Nl;
  inv[(size_t)n * 2 * l + m] = sc * c;
  inv[(size_t)n * 2 * l + l + m] = -sc * s;
}

// Decompose: read x (B, 2Nl, stride) at column offset coff, write DS (B,Nl,128)
// with d in cols 0..63 and s in cols 64..127.
__global__ void decompose_kernel(const float* __restrict__ xin, int inStride, int inOff,
                                 float* __restrict__ ds, int Nl, int lgNl,
                                 Mat84 ecd, Mat84 ecs) {
  int idx = blockIdx.x * 256 + threadIdx.x;
  int ci = idx & 15;
  int nb = idx >> 4;
  int n = nb & (Nl - 1);
  int b = nb >> lgNl;
  if (b >= 32) return;
  const float* r0 = xin + ((size_t)b * 2 * Nl + 2 * n) * inStride + inOff + ci * 4;
  float4 xe = *(const float4*)r0;
  float4 xo = *(const float4*)(r0 + inStride);
  float xa[8] = {xe.x, xe.y, xe.z, xe.w, xo.x, xo.y, xo.z, xo.w};
  float d[4] = {0, 0, 0, 0}, s[4] = {0, 0, 0, 0};
#pragma unroll
  for (int j = 0; j < 8; j++) {
    float v = xa[j];
#pragma unroll
    for (int kk = 0; kk < 4; kk++) {
      d[kk] = fmaf(v, ecd.v[j][kk], d[kk]);
      s[kk] = fmaf(v, ecs.v[j][kk], s[kk]);
    }
  }
  float* o = ds + ((size_t)b * Nl + n) * 128 + ci * 4;
  *(float4*)o = make_float4(d[0], d[1], d[2], d[3]);
  *(float4*)(o + 64) = make_float4(s[0], s[1], s[2], s[3]);
}

// Forward DFT GEMM with split-K + atomics: C[b] (M x 128) += A (M x K) @ B_b (K x 128)
__global__ __launch_bounds__(256) void fwd_gemm(const float* __restrict__ A,
                                                const float* __restrict__ Bm,
                                                float* __restrict__ C,
                                                int M, int K, int Kchunk) {
  __shared__ float As[32 * 68];
  __shared__ float Bs[32 * 128];
  int tid = threadIdx.x;
  int tm = tid >> 4, tn = tid & 15;
  int mt = blockIdx.x, b = blockIdx.y;
  int k0 = blockIdx.z * Kchunk;
  int k1 = k0 + Kchunk; if (k1 > K) k1 = K;
  const float* Bb = Bm + (size_t)b * K * 128;
  float acc[4][8];
#pragma unroll
  for (int i = 0; i < 4; i++)
#pragma unroll
    for (int j = 0; j < 8; j++) acc[i][j] = 0.f;
  int rr = tid >> 2, kg = (tid & 3) * 8;
  int arow = mt * 64 + rr;
  for (int kc = k0; kc < k1; kc += 32) {
    int kl = k1 - kc; if (kl > 32) kl = 32;
#pragma unroll
    for (int u = 0; u < 8; u++) {
      int kk = kg + u;
      float v = 0.f;
      if (arow < M && kc + kk < k1) v = A[(size_t)arow * K + kc + kk];
      As[kk * 68 + rr] = v;
    }
    for (int e = tid; e < 1024; e += 256) {
      int n4 = e & 31, kk = e >> 5;
      if (kk < kl)
        *(float4*)&Bs[kk * 128 + n4 * 4] = *(const float4*)&Bb[(size_t)(kc + kk) * 128 + n4 * 4];
    }
    __syncthreads();
    for (int kk = 0; kk < kl; kk++) {
      float4 a4 = *(const float4*)&As[kk * 68 + tm * 4];
      float4 b0 = *(const float4*)&Bs[kk * 128 + tn * 8];
      float4 b1 = *(const float4*)&Bs[kk * 128 + tn * 8 + 4];
      float av[4] = {a4.x, a4.y, a4.z, a4.w};
      float bv[8] = {b0.x, b0.y, b0.z, b0.w, b1.x, b1.y, b1.z, b1.w};
#pragma unroll
      for (int i = 0; i < 4; i++)
#pragma unroll
        for (int j = 0; j < 8; j++) acc[i][j] = fmaf(av[i], bv[j], acc[i][j]);
    }
    __syncthreads();
  }
#pragma unroll
  for (int i = 0; i < 4; i++) {
    int row = mt * 64 + tm * 4 + i;
    if (row < M) {
      float* Cr = C + ((size_t)b * M + row) * 128 + tn * 8;
#pragma unroll
      for (int j = 0; j < 8; j++) atomicAdd(&Cr[j], acc[i][j]);
    }
  }
}

// Spectral mix: UdSpec = Df*wA + Sf*wB ; UsSpec = Df*wC  (complex, per mode m)
// Dfs/Spec layout: (B, 2l, 128); rows 0..l-1 = Re, l..2l-1 = Im; cols [d|s] / [Ud|Us]
__global__ __launch_bounds__(256) void middle_kernel(
    const float* __restrict__ Dfs,
    const float* __restrict__ wAr, const float* __restrict__ wAi,
    const float* __restrict__ wBr, const float* __restrict__ wBi,
    const float* __restrict__ wCr, const float* __restrict__ wCi,
    float* __restrict__ Spec, int l) {
  __shared__ float din[4][2][128];
  __shared__ float red[4 * 4 * 4 * 64];
  int m = blockIdx.x, bg = blockIdx.y;
  int tid = threadIdx.x;
  int o = tid & 63, q = tid >> 6;
  for (int e = tid; e < 1024; e += 256) {
    int col = e & 127, row = (e >> 7) & 1, bb = e >> 8;
    size_t r = row ? (size_t)(l + m) : (size_t)m;
    din[bb][row][col] = Dfs[(((size_t)(bg * 4 + bb)) * 2 * l + r) * 128 + col];
  }
  __syncthreads();
  float acc[4][4];
#pragma unroll
  for (int i = 0; i < 4; i++)
#pragma unroll
    for (int j = 0; j < 4; j++) acc[i][j] = 0.f;
  for (int ii = 0; ii < 16; ii++) {
    int i = q * 16 + ii;
    size_t widx = ((size_t)(m * 64 + i)) * 64 + o;
    float war = wAr[widx], wai = wAi[widx];
    float wbr = wBr[widx], wbi = wBi[widx];
    float wcr = wCr[widx], wci = wCi[widx];
#pragma unroll
    for (int bb = 0; bb < 4; bb++) {
      float dr = din[bb][0][i], di_ = din[bb][1][i];
      float sr = din[bb][0][64 + i], si = din[bb][1][64 + i];
      acc[bb][0] += dr * war - di_ * wai + sr * wbr - si * wbi;
      acc[bb][1] += dr * wai + di_ * war + sr * wbi + si * wbr;
      acc[bb][2] += dr * wcr - di_ * wci;
      acc[bb][3] += dr * wci + di_ * wcr;
    }
  }
#pragma unroll
  for (int bb = 0; bb < 4; bb++)
#pragma unroll
    for (int v = 0; v < 4; v++) red[((q * 4 + bb) * 4 + v) * 64 + o] = acc[bb][v];
  __syncthreads();
  for (int e = tid; e < 1024; e += 256) {
    int oo = e & 63, v = (e >> 6) & 3, bb = e >> 8;
    float s = red[((0 * 4 + bb) * 4 + v) * 64 + oo] + red[((1 * 4 + bb) * 4 + v) * 64 + oo] +
              red[((2 * 4 + bb) * 4 + v) * 64 + oo] + red[((3 * 4 + bb) * 4 + v) * 64 + oo];
    int b = bg * 4 + bb;
    size_t row = (v & 1) ? (size_t)(l + m) : (size_t)m;
    int col = (v >= 2) ? 64 + oo : oo;
    Spec[((size_t)b * 2 * l + row) * 128 + col] = s;
  }
}

// Inverse DFT GEMM: Y_b (M x 128) = A (M x K) @ Spec_b (K x 128);
// cols 0..63 -> Ud store, 64..127 -> Us store (each (B, M, 64)).
__global__ __launch_bounds__(256) void inv_gemm(const float* __restrict__ A,
                                                const float* __restrict__ Bm,
                                                float* __restrict__ Cud,
                                                float* __restrict__ Cus,
                                                int M, int K) {
  __shared__ float As[32 * 68];
  __shared__ float Bs[32 * 128];
  int tid = threadIdx.x;
  int tm = tid >> 4, tn = tid & 15;
  int mt = blockIdx.x, b = blockIdx.y;
  const float* Bb = Bm + (size_t)b * K * 128;
  float acc[4][8];
#pragma unroll
  for (int i = 0; i < 4; i++)
#pragma unroll
    for (int j = 0; j < 8; j++) acc[i][j] = 0.f;
  int rr = tid >> 2, kg = (tid & 3) * 8;
  int arow = mt * 64 + rr;
  for (int kc = 0; kc < K; kc += 32) {
    int kl = K - kc; if (kl > 32) kl = 32;
#pragma unroll
    for (int u = 0; u < 8; u++) {
      int kk = kg + u;
      float v = 0.f;
      if (arow < M && kc + kk < K) v = A[(size_t)arow * K + kc + kk];
      As[kk * 68 + rr] = v;
    }
    for (int e = tid; e < 1024; e += 256) {
      int n4 = e & 31, kk = e >> 5;
      if (kk < kl)
        *(float4*)&Bs[kk * 128 + n4 * 4] = *(const float4*)&Bb[(size_t)(kc + kk) * 128 + n4 * 4];
    }
    __syncthreads();
    for (int kk = 0; kk < kl; kk++) {
      float4 a4 = *(const float4*)&As[kk * 68 + tm * 4];
      float4 b0 = *(const float4*)&Bs[kk * 128 + tn * 8];
      float4 b1 = *(const float4*)&Bs[kk * 128 + tn * 8 + 4];
      float av[4] = {a4.x, a4.y, a4.z, a4.w};
      float bv[8] = {b0.x, b0.y, b0.z, b0.w, b1.x, b1.y, b1.z, b1.w};
#pragma unroll
      for (int i = 0; i < 4; i++)
#pragma unroll
        for (int j = 0; j < 8; j++) acc[i][j] = fmaf(av[i], bv[j], acc[i][j]);
    }
    __syncthreads();
  }
#pragma unroll
  for (int i = 0; i < 4; i++) {
    int row = mt * 64 + tm * 4 + i;
    if (row < M) {
      size_t rb = ((size_t)b * M + row) * 64;
      if (tn < 8) {
#pragma unroll
        for (int j = 0; j < 8; j++) Cud[rb + tn * 8 + j] = acc[i][j];
      } else {
#pragma unroll
        for (int j = 0; j < 8; j++) Cus[rb + (tn - 8) * 8 + j] = acc[i][j];
      }
    }
  }
}

// t0: x(B,1,c,k) @ t0_w^T + t0_b ; input = s-half of DS (B,1,128)
__global__ void t0_kernel(const float* __restrict__ dsIn, const float* __restrict__ t0w,
                          const float* __restrict__ t0b, float* __restrict__ xout) {
  int idx = blockIdx.x * 256 + threadIdx.x;
  if (idx >= 512) return;
  int ci = idx & 15, b = idx >> 4;
  const float* xp = dsIn + (size_t)b * 128 + 64 + ci * 4;
  float x0 = xp[0], x1 = xp[1], x2 = xp[2], x3 = xp[3];
  float* op = xout + (size_t)b * 64 + ci * 4;
#pragma unroll
  for (int kk = 0; kk < 4; kk++)
    op[kk] = x0 * t0w[kk * 4 + 0] + x1 * t0w[kk * 4 + 1] + x2 * t0w[kk * 4 + 2] +
             x3 * t0w[kk * 4 + 3] + t0b[kk];
}

// Reconstruction: t = [x+Us | Ud]; out[2m] = t@RC_E, out[2m+1] = t@RC_O
__global__ void recon_kernel(const float* __restrict__ x, const float* __restrict__ Ud,
                             const float* __restrict__ Us, float* __restrict__ out,
                             int M, int lgM, Mat84 rce, Mat84 rco) {
  int idx = blockIdx.x * 256 + threadIdx.x;
  int ci = idx & 15;
  int nb = idx >> 4;
  int m = nb & (M - 1);
  int b = nb >> lgM;
  if (b >= 32) return;
  size_t basei = ((size_t)b * M + m) * 64 + ci * 4;
  float4 xv = *(const float4*)&x[basei];
  float4 uv = *(const float4*)&Us[basei];
  float4 dv = *(const float4*)&Ud[basei];
  float t[8] = {xv.x + uv.x, xv.y + uv.y, xv.z + uv.z, xv.w + uv.w, dv.x, dv.y, dv.z, dv.w};
  float e[4] = {0, 0, 0, 0}, o[4] = {0, 0, 0, 0};
#pragma unroll
  for (int j = 0; j < 8; j++) {
    float v = t[j];
#pragma unroll
    for (int kk = 0; kk < 4; kk++) {
      e[kk] = fmaf(v, rce.v[j][kk], e[kk]);
      o[kk] = fmaf(v, rco.v[j][kk], o[kk]);
    }
  }
  size_t ob = ((size_t)b * 2 * M + 2 * m) * 64 + ci * 4;
  *(float4*)&out[ob] = make_float4(e[0], e[1], e[2], e[3]);
  *(float4*)&out[ob + 64] = make_float4(o[0], o[1], o[2], o[3]);
}

// ---------------- host orchestration ---------------------------------------
extern "C" void kernel_launch(void* const* d_in, const int* in_sizes, int n_in,
                              void* d_out, int out_size, void* d_ws, size_t ws_size,
                              hipStream_t stream) {
  const float* x_in = (const float*)d_in[0];
  const float* t0w = (const float*)d_in[7];
  const float* t0b = (const float*)d_in[8];

  Mat84 ECS, ECD, RCE, RCO;
  compute_filters(ECS, ECD, RCE, RCO);

  // per-level geometry
  int NlA[13], lA[13], MA[13];
  size_t fOffA[13], iOffA[13], uOffA[13];
  size_t fo = 0, io = 0, uo = 0;
  for (int L = 0; L < 13; L++) {
    int Nl = 8192 >> (L + 1);
    int l = Nl / 2 + 1; if (l > 64) l = 64;
    NlA[L] = Nl; lA[L] = l; MA[L] = 2 * l;
    fOffA[L] = fo; fo += (size_t)2 * l * Nl;
    iOffA[L] = io; io += (size_t)2 * l * Nl;
    uOffA[L] = uo; uo += (size_t)32 * 64 * Nl;
  }

  // workspace carve (~254 MB)
  char* base = (char*)d_ws;
  size_t off = 0;
  auto alloc = [&](size_t bytes) -> float* {
    float* p = (float*)(base + off);
    off += (bytes + 255) & ~(size_t)255;
    return p;
  };
  float* DS0 = alloc((size_t)32 * 4096 * 128 * 4);  // level-even DS (and recon ping)
  float* DS1 = alloc((size_t)32 * 2048 * 128 * 4);  // level-odd DS (and recon pong)
  float* Ud  = alloc(uo * 4);
  float* Us  = alloc(uo * 4);
  float* Dfs = alloc((size_t)32 * 128 * 128 * 4);
  float* Spec = alloc((size_t)32 * 128 * 128 * 4);
  float* Ftw = alloc(fo * 4);
  float* Itw = alloc(io * 4);
  float* wT[6];
  for (int a = 0; a < 6; a++) wT[a] = alloc((size_t)64 * 64 * 64 * 4);

  // init: weight transpose + twiddle tables (re-done every call; ws is re-poisoned)
  Ptrs6 p6;
  for (int a = 0; a < 6; a++) { p6.src[a] = (const float*)d_in[1 + a]; p6.dst[a] = wT[a]; }
  transpose_w<<<dim3(64, 6), 256, 0, stream>>>(p6);
  for (int L = 0; L < 13; L++) {
    int nthr = lA[L] * NlA[L];
    twiddle_kernel<<<(nthr + 255) / 256, 256, 0, stream>>>(Ftw + fOffA[L], Itw + iOffA[L],
                                                           NlA[L], lA[L]);
  }

  // decomposition
  const float* cur = x_in;
  int stride = 64, coff = 0;
  for (int L = 0; L < 13; L++) {
    int Nl = NlA[L], l = lA[L], M = MA[L];
    float* ds = (L & 1) ? DS1 : DS0;
    int lg = 31 - __builtin_clz(Nl);
    decompose_kernel<<<Nl * 2, 256, 0, stream>>>(cur, stride, coff, ds, Nl, lg, ECD, ECS);
    hipMemsetAsync(Dfs, 0, (size_t)32 * M * 128 * 4, stream);
    const int Kchunk = 512;
    int Ksplit = (Nl + Kchunk - 1) / Kchunk;
    fwd_gemm<<<dim3((M + 63) / 64, 32, Ksplit), 256, 0, stream>>>(Ftw + fOffA[L], ds, Dfs, M,
                                                                  Nl, Kchunk);
    middle_kernel<<<dim3(l, 8), 256, 0, stream>>>(Dfs, wT[0], wT[1], wT[2], wT[3], wT[4], wT[5],
                                                  Spec, l);
    inv_gemm<<<dim3((Nl + 63) / 64, 32), 256, 0, stream>>>(Itw + iOffA[L], Spec,
                                                           Ud + uOffA[L], Us + uOffA[L], Nl, M);
    cur = ds; stride = 128; coff = 64;
  }

  // coarsest-level linear map: reads DS0 (level 12 output), writes x0 into DS1
  t0_kernel<<<2, 256, 0, stream>>>(DS0, t0w, t0b, DS1);

  // reconstruction (ping-pong DS1/DS0; final level writes d_out)
  float* curx = DS1;
  float* other = DS0;
  for (int i = 12; i >= 0; i--) {
    int M = NlA[i];
    int lg = 31 - __builtin_clz(M);
    float* dst = (i == 0) ? (float*)d_out : other;
    recon_kernel<<<M * 2, 256, 0, stream>>>(curx, Ud + uOffA[i], Us + uOffA[i], dst, M, lg,
                                            RCE, RCO);
    other = curx; curx = dst;
  }
}

// Round 2
// 764.492 us; speedup vs baseline: 1.7552x; 1.7552x over previous
//
#include <hip/hip_runtime.h>
#include <cmath>
#include <cstdint>

// ---------------------------------------------------------------------------
// MWT for B=32, N=8192, c=16, k=4, modes=64.
// 13 levels: decompose -> fwd truncated-DFT GEMM (bf16 MFMA) -> spectral mix
//            -> inv truncated-DFT GEMM (bf16 MFMA); t0; 13 recon levels.
// Precision plan: x-chain (s-path, t0, recon x) stays fp32; everything feeding
// the spectral branch (twiddles, d/s GEMM inputs, Spec, Ud/Us) is bf16 —
// those contributions are scaled by ~1/4096 weights, so bf16 error ~1e-5 abs.
// ---------------------------------------------------------------------------

typedef __attribute__((ext_vector_type(8))) short bf16x8;
typedef __attribute__((ext_vector_type(4))) float f32x4;

struct Mat84 { float v[8][4]; };
struct Ptrs6 { const float* src[6]; float* dst[6]; };

__device__ __host__ inline uint16_t f2bf(float f) {
  union { float f; uint32_t u; } cv; cv.f = f;
  uint32_t u = cv.u;
  return (uint16_t)((u + 0x7fffu + ((u >> 16) & 1u)) >> 16);
}
__device__ inline float bf2f(uint16_t h) { return __uint_as_float((uint32_t)h << 16); }

// ---------------- host: Alpert/Legendre filter construction (k=4) ----------
static double proj_half_h(const double* a, const double* b, bool upper) {
  double prod[7] = {0, 0, 0, 0, 0, 0, 0};
  for (int i = 0; i < 4; i++)
    for (int j = 0; j < 4; j++)
      prod[i + j] += a[i] * b[j];
  for (int n = 0; n < 7; n++)
    if (fabs(prod[n]) < 1e-8) prod[n] = 0.0;
  double s = 0.0;
  for (int n = 0; n < 7; n++) {
    double w = upper ? (1.0 - pow(0.5, n + 1)) / (n + 1) : pow(0.5, n + 1) / (n + 1);
    s += prod[n] * w;
  }
  return s;
}
static double polyval4(const double* c, double x) {
  return c[0] + x * (c[1] + x * (c[2] + x * c[3]));
}

static void compute_filters(Mat84& ecs, Mat84& ecd, Mat84& rce, Mat84& rco) {
  const double leg[4][4] = {{1, 0, 0, 0}, {0, 1, 0, 0}, {-0.5, 0, 1.5, 0}, {0, -1.5, 0, 2.5}};
  double phi_c[4][4] = {}, phi2x_c[4][4] = {};
  const double s2 = sqrt(2.0);
  for (int ki = 0; ki < 4; ki++) {
    double a[4] = {0, 0, 0, 0};
    for (int j = 3; j >= 0; j--) {
      double na[4];
      for (int t = 0; t < 4; t++) { double v = -a[t]; if (t > 0) v += 2.0 * a[t - 1]; na[t] = v; }
      na[0] += leg[ki][j];
      for (int t = 0; t < 4; t++) a[t] = na[t];
    }
    for (int t = 0; t < 4; t++) phi_c[ki][t] = sqrt(2.0 * ki + 1.0) * a[t];
    double bb[4] = {0, 0, 0, 0};
    for (int j = 3; j >= 0; j--) {
      double nb[4];
      for (int t = 0; t < 4; t++) { double v = -bb[t]; if (t > 0) v += 4.0 * bb[t - 1]; nb[t] = v; }
      nb[0] += leg[ki][j];
      for (int t = 0; t < 4; t++) bb[t] = nb[t];
    }
    for (int t = 0; t < 4; t++) phi2x_c[ki][t] = s2 * sqrt(2.0 * ki + 1.0) * bb[t];
  }
  double psi1[4][4] = {}, psi2[4][4] = {};
  for (int ki = 0; ki < 4; ki++) {
    for (int t = 0; t < 4; t++) { psi1[ki][t] = phi2x_c[ki][t]; psi2[ki][t] = 0.0; }
    for (int i = 0; i < 4; i++) {
      double p = proj_half_h(phi2x_c[ki], phi_c[i], false);
      for (int t = 0; t < 4; t++) { psi1[ki][t] -= p * phi_c[i][t]; psi2[ki][t] -= p * phi_c[i][t]; }
    }
    for (int j = 0; j < ki; j++) {
      double p = proj_half_h(phi2x_c[ki], psi1[j], false);
      for (int t = 0; t < 4; t++) { psi1[ki][t] -= p * psi1[j][t]; psi2[ki][t] -= p * psi2[j][t]; }
    }
    double n1 = proj_half_h(psi1[ki], psi1[ki], false);
    double n2 = proj_half_h(psi2[ki], psi2[ki], true);
    double nr = sqrt(n1 + n2);
    for (int t = 0; t < 4; t++) { psi1[ki][t] /= nr; psi2[ki][t] /= nr; }
    for (int t = 0; t < 4; t++) {
      if (fabs(psi1[ki][t]) < 1e-8) psi1[ki][t] = 0.0;
      if (fabs(psi2[ki][t]) < 1e-8) psi2[ki][t] = 0.0;
    }
  }
  const double tq[4] = {-0.8611363115940526, -0.3399810435848563,
                        0.3399810435848563, 0.8611363115940526};
  const double wq[4] = {0.34785484513745385, 0.6521451548625461,
                        0.6521451548625461, 0.34785484513745385};
  double H0[4][4], H1[4][4], G0[4][4], G1[4][4];
  for (int ki = 0; ki < 4; ki++)
    for (int kp = 0; kp < 4; kp++) {
      double h0 = 0, h1 = 0, g0 = 0, g1 = 0;
      for (int m = 0; m < 4; m++) {
        double xm = (tq[m] + 1.0) * 0.5, wm = wq[m] * 0.5;
        double pk = polyval4(phi_c[kp], xm);
        h0 += wm * polyval4(phi_c[ki], xm * 0.5) * pk;
        h1 += wm * polyval4(phi_c[ki], (xm + 1.0) * 0.5) * pk;
        g0 += wm * polyval4(psi1[ki], xm * 0.5) * pk;
        g1 += wm * polyval4(psi2[ki], (xm + 1.0) * 0.5) * pk;
      }
      H0[ki][kp] = h0 / s2; H1[ki][kp] = h1 / s2; G0[ki][kp] = g0 / s2; G1[ki][kp] = g1 / s2;
    }
  for (int i = 0; i < 4; i++)
    for (int j = 0; j < 4; j++) {
      if (fabs(H0[i][j]) < 1e-8) H0[i][j] = 0.0;
      if (fabs(H1[i][j]) < 1e-8) H1[i][j] = 0.0;
      if (fabs(G0[i][j]) < 1e-8) G0[i][j] = 0.0;
      if (fabs(G1[i][j]) < 1e-8) G1[i][j] = 0.0;
    }
  for (int j = 0; j < 4; j++)
    for (int kk = 0; kk < 4; kk++) {
      ecs.v[j][kk]     = (float)H0[kk][j];
      ecs.v[j + 4][kk] = (float)H1[kk][j];
      ecd.v[j][kk]     = (float)G0[kk][j];
      ecd.v[j + 4][kk] = (float)G1[kk][j];
      rce.v[j][kk]     = (float)H0[j][kk];
      rce.v[j + 4][kk] = (float)G0[j][kk];
      rco.v[j][kk]     = (float)H1[j][kk];
      rco.v[j + 4][kk] = (float)G1[j][kk];
    }
}

// ---------------- device kernels -------------------------------------------

// Transpose weights (i,o,m) -> (m,i,o), fp32.
__global__ void transpose_w(Ptrs6 p) {
  __shared__ float tile[64][65];
  int i = blockIdx.x, a = blockIdx.y;
  const float* w = p.src[a];
  float* wt = p.dst[a];
  int m = threadIdx.x & 63, orow = threadIdx.x >> 6;
  for (int o = orow; o < 64; o += 4) tile[o][m] = w[((i * 64 + o) << 6) + m];
  __syncthreads();
  int o = threadIdx.x & 63, mrow = threadIdx.x >> 6;
  for (int mm = mrow; mm < 64; mm += 4) wt[((mm * 64 + i) << 6) + o] = tile[o][mm];
}

// Fwd twiddles (128 x Nl, rows >= 2l zero) and inv twiddles (Nl x 128,
// cols >= 2l zero), both bf16.
__global__ void twiddle_kernel(uint16_t* __restrict__ Ftw, uint16_t* __restrict__ Itw,
                               int Nl, int l) {
  int idx = blockIdx.x * 256 + threadIdx.x;
  if (idx >= 128 * Nl) return;
  int n = idx % Nl, mm = idx / Nl;
  int m = (mm < l) ? mm : mm - l;
  int t = (m * n) & (Nl - 1);
  float ang = 6.2831853071795864769f * ((float)t / (float)Nl);
  float s, c;
  sincosf(ang, &s, &c);
  float fv = 0.f, iv = 0.f;
  float cm = (m == 0 || 2 * m == Nl) ? 1.0f : 2.0f;
  float sc = cm / (float)Nl;
  if (mm < l)          { fv = c;  iv = sc * c; }
  else if (mm < 2 * l) { fv = -s; iv = -sc * s; }
  Ftw[(size_t)mm * Nl + n] = f2bf(fv);
  Itw[(size_t)n * 128 + mm] = f2bf(iv);
}

// Decompose: in (b, 2Nl, 64) fp32 -> s32 (b, Nl, 64) fp32 (x-chain)
//            + dsbfT (b, 128, Nl) bf16, rows 0..63 = d, 64..127 = s (GEMM B^T).
__global__ void decompose_kernel(const float* __restrict__ xin, float* __restrict__ s32,
                                 uint16_t* __restrict__ dsbfT, int Nl, int lgNl,
                                 Mat84 ecd, Mat84 ecs) {
  int idx = blockIdx.x * 256 + threadIdx.x;
  int ci = idx & 15;
  int nb = idx >> 4;
  int n = nb & (Nl - 1);
  int b = nb >> lgNl;
  if (b >= 32) return;
  const float* r0 = xin + ((size_t)(b * 2 * Nl + 2 * n)) * 64 + ci * 4;
  float4 xe = *(const float4*)r0;
  float4 xo = *(const float4*)(r0 + 64);
  float xa[8] = {xe.x, xe.y, xe.z, xe.w, xo.x, xo.y, xo.z, xo.w};
  float d[4] = {0, 0, 0, 0}, s[4] = {0, 0, 0, 0};
#pragma unroll
  for (int j = 0; j < 8; j++) {
    float v = xa[j];
#pragma unroll
    for (int kk = 0; kk < 4; kk++) {
      d[kk] = fmaf(v, ecd.v[j][kk], d[kk]);
      s[kk] = fmaf(v, ecs.v[j][kk], s[kk]);
    }
  }
  *(float4*)&s32[((size_t)b * Nl + n) * 64 + ci * 4] = make_float4(s[0], s[1], s[2], s[3]);
  size_t tb = ((size_t)b * 128 + ci * 4) * Nl + n;
#pragma unroll
  for (int kk = 0; kk < 4; kk++) {
    dsbfT[tb + (size_t)kk * Nl] = f2bf(d[kk]);
    dsbfT[tb + (size_t)(64 + kk) * Nl] = f2bf(s[kk]);
  }
}

// Fwd DFT GEMM (bf16 MFMA): Dfs[z][b] (128x128 fp32) = A(128xK) @ B_b^T(K x 128)
// A row-major (m,k); BT rows are output-cols, contiguous in k. Split-K slabs.
__global__ __launch_bounds__(256) void fwd_mfma(const uint16_t* __restrict__ A,
                                                const uint16_t* __restrict__ BT,
                                                float* __restrict__ Dfs,
                                                int K, int Kchunk) {
  __shared__ uint16_t As[128 * 32];
  __shared__ uint16_t Bs[128 * 32];
  int tid = threadIdx.x;
  int b = blockIdx.x, z = blockIdx.y;
  int k0 = z * Kchunk;
  int k1 = k0 + Kchunk; if (k1 > K) k1 = K;
  const uint16_t* Bb = BT + (size_t)b * 128 * K;
  int w = tid >> 6, lane = tid & 63;
  int wr = w >> 1, wc = w & 1;
  int lr = lane & 15, q = lane >> 4;
  f32x4 acc[4][4];
#pragma unroll
  for (int i = 0; i < 4; i++)
#pragma unroll
    for (int j = 0; j < 4; j++) acc[i][j] = (f32x4){0.f, 0.f, 0.f, 0.f};
  for (int kc = k0; kc < k1; kc += 32) {
    for (int s = tid; s < 512; s += 256) {
      int row = s >> 2, k8 = (s & 3) * 8;
      int kg = kc + k8;
      uint16_t ta[8], tb[8];
      if (kg + 8 <= k1) {
        *(uint4*)ta = *(const uint4*)&A[(size_t)row * K + kg];
        *(uint4*)tb = *(const uint4*)&Bb[(size_t)row * K + kg];
      } else {
#pragma unroll
        for (int j = 0; j < 8; j++) {
          ta[j] = (kg + j < k1) ? A[(size_t)row * K + kg + j] : (uint16_t)0;
          tb[j] = (kg + j < k1) ? Bb[(size_t)row * K + kg + j] : (uint16_t)0;
        }
      }
      *(uint4*)&As[row * 32 + k8] = *(const uint4*)ta;
      *(uint4*)&Bs[row * 32 + k8] = *(const uint4*)tb;
    }
    __syncthreads();
    bf16x8 af[4], bfv[4];
#pragma unroll
    for (int t = 0; t < 4; t++) {
      af[t]  = *(const bf16x8*)&As[(wr * 64 + t * 16 + lr) * 32 + q * 8];
      bfv[t] = *(const bf16x8*)&Bs[(wc * 64 + t * 16 + lr) * 32 + q * 8];
    }
#pragma unroll
    for (int mt = 0; mt < 4; mt++)
#pragma unroll
      for (int nt = 0; nt < 4; nt++)
        acc[mt][nt] = __builtin_amdgcn_mfma_f32_16x16x32_bf16(af[mt], bfv[nt], acc[mt][nt], 0, 0, 0);
    __syncthreads();
  }
  float* Cb = Dfs + ((size_t)z * 32 + b) * 128 * 128;
#pragma unroll
  for (int mt = 0; mt < 4; mt++) {
    int row0 = wr * 64 + mt * 16 + q * 4;
#pragma unroll
    for (int nt = 0; nt < 4; nt++) {
      int col = wc * 64 + nt * 16 + lr;
#pragma unroll
      for (int r = 0; r < 4; r++)
        Cb[(size_t)(row0 + r) * 128 + col] = acc[mt][nt][r];
    }
  }
}

// Spectral mix: sums split-K slabs, does the per-mode complex mixing,
// writes Spec transposed bf16 (b, col 128, krow 128) for the inverse GEMM.
__global__ __launch_bounds__(256) void middle_kernel(
    const float* __restrict__ Dfs, int nz,
    const float* __restrict__ wAr, const float* __restrict__ wAi,
    const float* __restrict__ wBr, const float* __restrict__ wBi,
    const float* __restrict__ wCr, const float* __restrict__ wCi,
    uint16_t* __restrict__ SpecT, int l) {
  __shared__ float din[4][2][128];
  __shared__ float red[4096];
  int m = blockIdx.x, bg = blockIdx.y;
  int tid = threadIdx.x;
  int o = tid & 63, q = tid >> 6;
  for (int e = tid; e < 1024; e += 256) {
    int col = e & 127, row = (e >> 7) & 1, bb = e >> 8;
    int b = bg * 4 + bb;
    size_t r = row ? (size_t)(l + m) : (size_t)m;
    float s = 0.f;
    for (int z = 0; z < nz; z++)
      s += Dfs[(((size_t)z * 32 + b) * 128 + r) * 128 + col];
    din[bb][row][col] = s;
  }
  __syncthreads();
  float acc[4][4];
#pragma unroll
  for (int i = 0; i < 4; i++)
#pragma unroll
    for (int j = 0; j < 4; j++) acc[i][j] = 0.f;
  for (int ii = 0; ii < 16; ii++) {
    int i = q * 16 + ii;
    size_t widx = ((size_t)(m * 64 + i)) * 64 + o;
    float war = wAr[widx], wai = wAi[widx];
    float wbr = wBr[widx], wbi = wBi[widx];
    float wcr = wCr[widx], wci = wCi[widx];
#pragma unroll
    for (int bb = 0; bb < 4; bb++) {
      float dr = din[bb][0][i], di_ = din[bb][1][i];
      float sr = din[bb][0][64 + i], si = din[bb][1][64 + i];
      acc[bb][0] += dr * war - di_ * wai + sr * wbr - si * wbi;
      acc[bb][1] += dr * wai + di_ * war + sr * wbi + si * wbr;
      acc[bb][2] += dr * wcr - di_ * wci;
      acc[bb][3] += dr * wci + di_ * wcr;
    }
  }
#pragma unroll
  for (int bb = 0; bb < 4; bb++)
#pragma unroll
    for (int v = 0; v < 4; v++) red[((q * 4 + bb) * 4 + v) * 64 + o] = acc[bb][v];
  __syncthreads();
  for (int e = tid; e < 1024; e += 256) {
    int oo = e & 63, v = (e >> 6) & 3, bb = e >> 8;
    float s = red[((0 * 4 + bb) * 4 + v) * 64 + oo] + red[((1 * 4 + bb) * 4 + v) * 64 + oo] +
              red[((2 * 4 + bb) * 4 + v) * 64 + oo] + red[((3 * 4 + bb) * 4 + v) * 64 + oo];
    int b = bg * 4 + bb;
    int krow = (v & 1) ? (l + m) : m;
    int col = (v >= 2) ? 64 + oo : oo;
    SpecT[((size_t)b * 128 + col) * 128 + krow] = f2bf(s);
  }
}

// Inv DFT GEMM (bf16 MFMA): Y_b (Nl x 128) = Itw(Nl x 128, zero-padded cols)
// @ Spec_b (128 x 128, rows >= 2l treated as zero). Cols 0..63 -> Ud, 64..127 -> Us.
__global__ __launch_bounds__(256) void inv_mfma(const uint16_t* __restrict__ A,
                                                const uint16_t* __restrict__ SpecT,
                                                uint16_t* __restrict__ Ud,
                                                uint16_t* __restrict__ Us,
                                                int Nl, int K2l) {
  __shared__ uint16_t As[128 * 32];
  __shared__ uint16_t Bs[128 * 32];
  int tid = threadIdx.x;
  int n0 = blockIdx.x * 128, b = blockIdx.y;
  const uint16_t* Bb = SpecT + (size_t)b * 128 * 128;
  int w = tid >> 6, lane = tid & 63;
  int wr = w >> 1, wc = w & 1;
  int lr = lane & 15, q = lane >> 4;
  f32x4 acc[4][4];
#pragma unroll
  for (int i = 0; i < 4; i++)
#pragma unroll
    for (int j = 0; j < 4; j++) acc[i][j] = (f32x4){0.f, 0.f, 0.f, 0.f};
  for (int kc = 0; kc < 128; kc += 32) {
    for (int s = tid; s < 512; s += 256) {
      int row = s >> 2, k8 = (s & 3) * 8;
      int kg = kc + k8;
      *(uint4*)&As[row * 32 + k8] = *(const uint4*)&A[((size_t)(n0 + row)) * 128 + kg];
      uint16_t tb[8];
      if (kg + 8 <= K2l) {
        *(uint4*)tb = *(const uint4*)&Bb[(size_t)row * 128 + kg];
      } else {
#pragma unroll
        for (int j = 0; j < 8; j++)
          tb[j] = (kg + j < K2l) ? Bb[(size_t)row * 128 + kg + j] : (uint16_t)0;
      }
      *(uint4*)&Bs[row * 32 + k8] = *(const uint4*)tb;
    }
    __syncthreads();
    bf16x8 af[4], bfv[4];
#pragma unroll
    for (int t = 0; t < 4; t++) {
      af[t]  = *(const bf16x8*)&As[(wr * 64 + t * 16 + lr) * 32 + q * 8];
      bfv[t] = *(const bf16x8*)&Bs[(wc * 64 + t * 16 + lr) * 32 + q * 8];
    }
#pragma unroll
    for (int mt = 0; mt < 4; mt++)
#pragma unroll
      for (int nt = 0; nt < 4; nt++)
        acc[mt][nt] = __builtin_amdgcn_mfma_f32_16x16x32_bf16(af[mt], bfv[nt], acc[mt][nt], 0, 0, 0);
    __syncthreads();
  }
#pragma unroll
  for (int mt = 0; mt < 4; mt++) {
    int row0 = wr * 64 + mt * 16 + q * 4;
#pragma unroll
    for (int nt = 0; nt < 4; nt++) {
      int col = wc * 64 + nt * 16 + lr;
#pragma unroll
      for (int r = 0; r < 4; r++) {
        int n = n0 + row0 + r;
        if (n < Nl) {
          uint16_t v = f2bf(acc[mt][nt][r]);
          if (col < 64) Ud[((size_t)b * Nl + n) * 64 + col] = v;
          else          Us[((size_t)b * Nl + n) * 64 + (col - 64)] = v;
        }
      }
    }
  }
}

// t0: x(B,1,c,k) @ t0_w^T + t0_b ; input = s32 of last level (b,1,64) fp32.
__global__ void t0_kernel(const float* __restrict__ dsIn, const float* __restrict__ t0w,
                          const float* __restrict__ t0b, float* __restrict__ xout) {
  int idx = blockIdx.x * 256 + threadIdx.x;
  if (idx >= 512) return;
  int ci = idx & 15, b = idx >> 4;
  const float* xp = dsIn + (size_t)b * 64 + ci * 4;
  float x0 = xp[0], x1 = xp[1], x2 = xp[2], x3 = xp[3];
  float* op = xout + (size_t)b * 64 + ci * 4;
#pragma unroll
  for (int kk = 0; kk < 4; kk++)
    op[kk] = x0 * t0w[kk * 4 + 0] + x1 * t0w[kk * 4 + 1] + x2 * t0w[kk * 4 + 2] +
             x3 * t0w[kk * 4 + 3] + t0b[kk];
}

// Reconstruction: t = [x+Us | Ud] (Ud/Us bf16); out[2m]=t@RC_E, out[2m+1]=t@RC_O
__global__ void recon_kernel(const float* __restrict__ x, const uint16_t* __restrict__ Ud,
                             const uint16_t* __restrict__ Us, float* __restrict__ out,
                             int M, int lgM, Mat84 rce, Mat84 rco) {
  int idx = blockIdx.x * 256 + threadIdx.x;
  int ci = idx & 15;
  int nb = idx >> 4;
  int m = nb & (M - 1);
  int b = nb >> lgM;
  if (b >= 32) return;
  size_t basei = ((size_t)b * M + m) * 64 + ci * 4;
  float4 xv = *(const float4*)&x[basei];
  ushort4 uu = *(const ushort4*)&Us[basei];
  ushort4 dd = *(const ushort4*)&Ud[basei];
  float t[8] = {xv.x + bf2f(uu.x), xv.y + bf2f(uu.y), xv.z + bf2f(uu.z), xv.w + bf2f(uu.w),
                bf2f(dd.x), bf2f(dd.y), bf2f(dd.z), bf2f(dd.w)};
  float e[4] = {0, 0, 0, 0}, o[4] = {0, 0, 0, 0};
#pragma unroll
  for (int j = 0; j < 8; j++) {
    float v = t[j];
#pragma unroll
    for (int kk = 0; kk < 4; kk++) {
      e[kk] = fmaf(v, rce.v[j][kk], e[kk]);
      o[kk] = fmaf(v, rco.v[j][kk], o[kk]);
    }
  }
  size_t ob = ((size_t)b * 2 * M + 2 * m) * 64 + ci * 4;
  *(float4*)&out[ob] = make_float4(e[0], e[1], e[2], e[3]);
  *(float4*)&out[ob + 64] = make_float4(o[0], o[1], o[2], o[3]);
}

// ---------------- host orchestration ---------------------------------------
extern "C" void kernel_launch(void* const* d_in, const int* in_sizes, int n_in,
                              void* d_out, int out_size, void* d_ws, size_t ws_size,
                              hipStream_t stream) {
  const float* x_in = (const float*)d_in[0];
  const float* t0w = (const float*)d_in[7];
  const float* t0b = (const float*)d_in[8];

  Mat84 ECS, ECD, RCE, RCO;
  compute_filters(ECS, ECD, RCE, RCO);

  int NlA[13], lA[13];
  size_t fOff[13], iOff[13], uOff[13];
  size_t fo = 0, io = 0, uo = 0;
  for (int L = 0; L < 13; L++) {
    int Nl = 8192 >> (L + 1);
    int l = Nl / 2 + 1; if (l > 64) l = 64;
    NlA[L] = Nl; lA[L] = l;
    fOff[L] = fo; fo += (size_t)128 * Nl;
    iOff[L] = io; io += (size_t)Nl * 128;
    uOff[L] = uo; uo += (size_t)32 * 64 * Nl;
  }
  io += 128 * 128;  // inv_mfma A-staging slack for Nl<128 levels

  char* base = (char*)d_ws;
  size_t off = 0;
  auto alloc = [&](size_t bytes) -> char* {
    char* p = base + off;
    off += (bytes + 255) & ~(size_t)255;
    return p;
  };
  float*    DS0   = (float*)alloc((size_t)32 * 4096 * 64 * 4);
  float*    DS1   = (float*)alloc((size_t)32 * 4096 * 64 * 4);
  uint16_t* Ud    = (uint16_t*)alloc(uo * 2);
  uint16_t* Us    = (uint16_t*)alloc(uo * 2);
  float*    Dfs   = (float*)alloc((size_t)8 * 32 * 128 * 128 * 4);
  uint16_t* SpecT = (uint16_t*)alloc((size_t)32 * 128 * 128 * 2);
  uint16_t* DSbf  = (uint16_t*)alloc((size_t)32 * 128 * 4096 * 2);
  uint16_t* Ftw   = (uint16_t*)alloc(fo * 2);
  uint16_t* Itw   = (uint16_t*)alloc(io * 2);
  float* wT[6];
  for (int a = 0; a < 6; a++) wT[a] = (float*)alloc((size_t)64 * 64 * 64 * 4);

  Ptrs6 p6;
  for (int a = 0; a < 6; a++) { p6.src[a] = (const float*)d_in[1 + a]; p6.dst[a] = wT[a]; }
  transpose_w<<<dim3(64, 6), 256, 0, stream>>>(p6);
  for (int L = 0; L < 13; L++) {
    int nthr = 128 * NlA[L];
    twiddle_kernel<<<(nthr + 255) / 256, 256, 0, stream>>>(Ftw + fOff[L], Itw + iOff[L],
                                                           NlA[L], lA[L]);
  }

  // decomposition
  const float* cur = x_in;
  for (int L = 0; L < 13; L++) {
    int Nl = NlA[L], l = lA[L], K = Nl;
    float* s32 = (L & 1) ? DS1 : DS0;
    int lg = 31 - __builtin_clz(Nl);
    decompose_kernel<<<Nl * 2, 256, 0, stream>>>(cur, s32, DSbf, Nl, lg, ECD, ECS);
    int nz = K / 64; if (nz < 1) nz = 1; if (nz > 8) nz = 8;
    int Kchunk = (((K + nz - 1) / nz) + 31) & ~31;
    fwd_mfma<<<dim3(32, nz), 256, 0, stream>>>(Ftw + fOff[L], DSbf, Dfs, K, Kchunk);
    middle_kernel<<<dim3(l, 8), 256, 0, stream>>>(Dfs, nz, wT[0], wT[1], wT[2], wT[3], wT[4],
                                                  wT[5], SpecT, l);
    inv_mfma<<<dim3((Nl + 127) / 128, 32), 256, 0, stream>>>(Itw + iOff[L], SpecT,
                                                             Ud + uOff[L], Us + uOff[L],
                                                             Nl, 2 * l);
    cur = s32;
  }

  // coarsest-level linear map: reads DS0 (level-12 s), writes x0 into DS1
  t0_kernel<<<2, 256, 0, stream>>>(DS0, t0w, t0b, DS1);

  // reconstruction (ping-pong DS1/DS0; final level writes d_out)
  float* curx = DS1;
  float* other = DS0;
  for (int i = 12; i >= 0; i--) {
    int M = NlA[i];
    int lg = 31 - __builtin_clz(M);
    float* dst = (i == 0) ? (float*)d_out : other;
    recon_kernel<<<M * 2, 256, 0, stream>>>(curx, Ud + uOff[i], Us + uOff[i], dst, M, lg,
                                            RCE, RCO);
    other = curx; curx = dst;
  }
}